// Round 7
// baseline (230.157 us; speedup 1.0000x reference)
//
#include <hip/hip_runtime.h>

#define NB 65536
#define D 64
#define SLOPE 0.2f
#define NPHASE 4

typedef _Float16 h2f __attribute__((ext_vector_type(2)));

__device__ __forceinline__ h2f as_h2(unsigned x) {
    union { unsigned u; h2f h; } v; v.u = x; return v.h;
}

struct UH { h2f h0, h1, h2, h3; };

__device__ __forceinline__ float dot8(uint4 w, const UH& u, float acc) {
#if __has_builtin(__builtin_amdgcn_fdot2)
    acc = __builtin_amdgcn_fdot2(as_h2(w.x), u.h0, acc, false);
    acc = __builtin_amdgcn_fdot2(as_h2(w.y), u.h1, acc, false);
    acc = __builtin_amdgcn_fdot2(as_h2(w.z), u.h2, acc, false);
    acc = __builtin_amdgcn_fdot2(as_h2(w.w), u.h3, acc, false);
#else
    h2f t0 = as_h2(w.x) * u.h0 + as_h2(w.y) * u.h1;
    h2f t1 = as_h2(w.z) * u.h2 + as_h2(w.w) * u.h3;
    acc += (float)t0.x + (float)t0.y + (float)t1.x + (float)t1.y;
#endif
    return acc;
}

__device__ __forceinline__ float reduce8(float v) {
#pragma unroll
    for (int off = 1; off <= 4; off <<= 1)
        v += __shfl_xor(v, off, 64);
    return v;
}
__device__ __forceinline__ float reduce64(float v) {
#pragma unroll
    for (int off = 1; off <= 32; off <<= 1)
        v += __shfl_xor(v, off, 64);
    return v;
}

__device__ __forceinline__ int lower_bound(const int* __restrict__ seg, int n, int key) {
    int lo = 0, hi = n;
    while (lo < hi) {
        int mid = (lo + hi) >> 1;
        if (seg[mid] < key) lo = mid + 1;
        else hi = mid;
    }
    return lo;
}

// ---------------- pre-pass: f16 entity table (linear 128B rows) + segment offsets ----------------
__global__ __launch_bounds__(256)
void prepass(const float4* __restrict__ ef4, uint2* __restrict__ efh, int n4,
             const int* __restrict__ a_seg, int Ta, int* __restrict__ offs_a,
             const int* __restrict__ c_seg, int Tc, int* __restrict__ offs_c)
{
    const int t = blockIdx.x * blockDim.x + threadIdx.x;
    if (t < n4) {
        float4 v = ef4[t];
        h2f a = { (_Float16)v.x, (_Float16)v.y };
        h2f b = { (_Float16)v.z, (_Float16)v.w };
        union { h2f h; unsigned u; } ca, cb; ca.h = a; cb.h = b;
        efh[t] = make_uint2(ca.u, cb.u);
    }
    if (t < Ta) {
        int s = a_seg[t];
        if (t == 0) offs_a[0] = 0;
        else if (a_seg[t - 1] != s) offs_a[s] = t;
        if (t == Ta - 1) offs_a[s + 1] = Ta;
    }
    if (t < Tc) {
        int s = c_seg[t];
        if (t == 0) offs_c[0] = 0;
        else if (c_seg[t - 1] != s) offs_c[s] = t;
        if (t == Tc - 1) offs_c[s + 1] = Tc;
    }
}

// ---------------- phased gather: wave = (phase p over id-range, row b) ----------------
// Full 128B f16 rows (one line-request per row); range-predicated re-scan per phase.
__global__ __launch_bounds__(256)
void gather_p(const int* __restrict__ user_id,
              const int* __restrict__ a_ids, const int* __restrict__ offs_a,
              const int* __restrict__ c_ids, const int* __restrict__ offs_c,
              const float* __restrict__ uf,
              const uint4* __restrict__ efh,   // 8 uint4 per row
              int range_sz,
              float* __restrict__ part)        // part[(p*2+aspect)*NB + b]
{
    const int wid  = blockIdx.x * 4 + (threadIdx.x >> 6);
    const int lane = threadIdx.x & 63;
    const int p = wid >> 16;          // phase 0..3 (slow -> time-separated)
    const int b = wid & 0xFFFF;
    const int rg = lane >> 3;         // row 0..7 within tile
    const int c  = lane & 7;          // dim chunk 0..7 (dims 8c..8c+7)

    const int lo = p * range_sz;
    const int hi = lo + range_sz;

    const int uid = user_id[b];
    const float4 ua = reinterpret_cast<const float4*>(uf)[uid * 16 + 2 * c];
    const float4 ub = reinterpret_cast<const float4*>(uf)[uid * 16 + 2 * c + 1];
    UH uh;
    uh.h0 = h2f{ (_Float16)ua.x, (_Float16)ua.y };
    uh.h1 = h2f{ (_Float16)ua.z, (_Float16)ua.w };
    uh.h2 = h2f{ (_Float16)ub.x, (_Float16)ub.y };
    uh.h3 = h2f{ (_Float16)ub.z, (_Float16)ub.w };

    auto gath = [&](const int* __restrict__ ids, int s, int e) -> float {
        float acc = 0.f;
        int t = s;
        for (; t + 16 <= e; t += 16) {
            const int id0 = ids[t + rg];
            const int id1 = ids[t + 8 + rg];
            if (id0 >= lo && id0 < hi) {
                const uint4 w0 = efh[id0 * 8 + c];
                acc = dot8(w0, uh, acc);
            }
            if (id1 >= lo && id1 < hi) {
                const uint4 w1 = efh[id1 * 8 + c];
                acc = dot8(w1, uh, acc);
            }
        }
        if (t + rg < e) {
            const int id0 = ids[t + rg];
            if (id0 >= lo && id0 < hi) {
                const uint4 w0 = efh[id0 * 8 + c];
                acc = dot8(w0, uh, acc);
            }
        }
        t += 8;
        if (t + rg < e) {
            const int id1 = ids[t + rg];
            if (id1 >= lo && id1 < hi) {
                const uint4 w1 = efh[id1 * 8 + c];
                acc = dot8(w1, uh, acc);
            }
        }
        return reduce64(acc);
    };

    const float pa = gath(a_ids, offs_a[b], offs_a[b + 1]);
    const float pc = gath(c_ids, offs_c[b], offs_c[b + 1]);
    if (lane == 0) {
        part[(p * 2 + 0) * NB + b] = pa;
        part[(p * 2 + 1) * NB + b] = pc;
    }
}

// ---------------- final: softmax + combine partials + outputs ----------------
__global__ __launch_bounds__(256)
void final_k(const int* __restrict__ user_id,
             const int* __restrict__ offs_a, const int* __restrict__ offs_c,
             const float* __restrict__ uf, const float* __restrict__ relation_k,
             const float* __restrict__ part, float* __restrict__ out)
{
    const int b    = blockIdx.x * 4 + (threadIdx.x >> 6);
    const int lane = threadIdx.x & 63;
    const int c = lane & 7;

    const int uid = user_id[b];
    const float4 ua = reinterpret_cast<const float4*>(uf)[uid * 16 + 2 * c];
    const float4 ub = reinterpret_cast<const float4*>(uf)[uid * 16 + 2 * c + 1];

    float p0 = 0.f, p1 = 0.f, p2 = 0.f;
    {
        const float uv[8] = {ua.x, ua.y, ua.z, ua.w, ub.x, ub.y, ub.z, ub.w};
#pragma unroll
        for (int j = 0; j < 8; ++j) {
            const int row = 8 * c + j;
            p0 += uv[j] * relation_k[row * 3 + 0];
            p1 += uv[j] * relation_k[row * 3 + 1];
            p2 += uv[j] * relation_k[row * 3 + 2];
        }
    }
    float l0 = reduce8(p0), l1 = reduce8(p1), l2 = reduce8(p2);
    l0 = l0 > 0.f ? l0 : SLOPE * l0;
    l1 = l1 > 0.f ? l1 : SLOPE * l1;
    l2 = l2 > 0.f ? l2 : SLOPE * l2;
    const float m  = fmaxf(l0, fmaxf(l1, l2));
    const float e0 = __expf(l0 - m);
    const float e1 = __expf(l1 - m);
    const float e2 = __expf(l2 - m);
    const float inv = 1.0f / (e0 + e1 + e2);
    const float s0 = e0 * inv, s1 = e1 * inv, s2 = e2 * inv;

    // 8 partial slots: p*2 + aspect; lanes 0..7 load in parallel
    const float pv = (lane < 8) ? part[lane * NB + b] : 0.f;
    const float c_a_sum = __shfl(pv, 0, 64) + __shfl(pv, 2, 64) +
                          __shfl(pv, 4, 64) + __shfl(pv, 6, 64);
    const float c_c_sum = __shfl(pv, 1, 64) + __shfl(pv, 3, 64) +
                          __shfl(pv, 5, 64) + __shfl(pv, 7, 64);
    const float na = (float)(offs_a[b + 1] - offs_a[b]);
    const float nc = (float)(offs_c[b + 1] - offs_c[b]);
    const float c_a = c_a_sum / na;
    const float c_c = c_c_sum / nc;

    const float pred = (c_a * s0 + c_c * s1) / (s0 + s1);

    if (lane == 0) {
        out[b]          = pred;
        out[4 * NB + b] = c_a;
        out[5 * NB + b] = c_c;
    }
    if (lane < 3) {
        const float sv = (lane == 0) ? s0 : ((lane == 1) ? s1 : s2);
        out[NB + 3 * b + lane] = sv;
    }
}

// ---------------- fallback (no workspace): bsearch + fp32 ----------------
__global__ __launch_bounds__(256)
void aspect_fallback(const int* __restrict__ user_id,
                     const int* __restrict__ a_ids, const int* __restrict__ a_seg, int Ta,
                     const int* __restrict__ c_ids, const int* __restrict__ c_seg, int Tc,
                     const float* __restrict__ user_factors,
                     const float4* __restrict__ ef4,
                     const float* __restrict__ relation_k,
                     float* __restrict__ out)
{
    const int b    = blockIdx.x * 4 + (threadIdx.x >> 6);
    const int lane = threadIdx.x & 63;
    const int g = lane >> 4, k = lane & 15;

    const int uid = user_id[b];
    const float4 u4 = reinterpret_cast<const float4*>(user_factors)[uid * 16 + k];

    float p0 = 0.f, p1 = 0.f, p2 = 0.f;
    {
        const float uv[4] = {u4.x, u4.y, u4.z, u4.w};
#pragma unroll
        for (int j = 0; j < 4; ++j) {
            const int row = 4 * k + j;
            p0 += uv[j] * relation_k[row * 3 + 0];
            p1 += uv[j] * relation_k[row * 3 + 1];
            p2 += uv[j] * relation_k[row * 3 + 2];
        }
    }
#pragma unroll
    for (int off = 1; off <= 8; off <<= 1) {
        p0 += __shfl_xor(p0, off, 64);
        p1 += __shfl_xor(p1, off, 64);
        p2 += __shfl_xor(p2, off, 64);
    }
    float l0 = p0 > 0.f ? p0 : SLOPE * p0;
    float l1 = p1 > 0.f ? p1 : SLOPE * p1;
    float l2 = p2 > 0.f ? p2 : SLOPE * p2;
    const float m  = fmaxf(l0, fmaxf(l1, l2));
    const float e0 = __expf(l0 - m), e1 = __expf(l1 - m), e2 = __expf(l2 - m);
    const float inv = 1.0f / (e0 + e1 + e2);
    const float s0 = e0 * inv, s1 = e1 * inv, s2 = e2 * inv;

    auto gd = [&](const int* __restrict__ ids, int s, int e) -> float {
        float ax = 0.f, ay = 0.f, az = 0.f, aw = 0.f;
        int t = s;
        for (; t + 4 <= e; t += 4) {
            const float4 v0 = ef4[ids[t + g] * 16 + k];
            ax += v0.x; ay += v0.y; az += v0.z; aw += v0.w;
        }
        if (t + g < e) {
            const float4 v0 = ef4[ids[t + g] * 16 + k];
            ax += v0.x; ay += v0.y; az += v0.z; aw += v0.w;
        }
        return reduce64(ax * u4.x + ay * u4.y + az * u4.z + aw * u4.w);
    };

    const int sa = lower_bound(a_seg, Ta, b), ea = lower_bound(a_seg, Ta, b + 1);
    const int sc = lower_bound(c_seg, Tc, b), ec = lower_bound(c_seg, Tc, b + 1);
    const float c_a = gd(a_ids, sa, ea) / (float)(ea - sa);
    const float c_c = gd(c_ids, sc, ec) / (float)(ec - sc);
    const float pred = (c_a * s0 + c_c * s1) / (s0 + s1);

    if (lane == 0) {
        out[b]          = pred;
        out[4 * NB + b] = c_a;
        out[5 * NB + b] = c_c;
    }
    if (lane < 3) {
        const float sv = (lane == 0) ? s0 : ((lane == 1) ? s1 : s2);
        out[NB + 3 * b + lane] = sv;
    }
}

extern "C" void kernel_launch(void* const* d_in, const int* in_sizes, int n_in,
                              void* d_out, int out_size, void* d_ws, size_t ws_size,
                              hipStream_t stream) {
    const int*   user_id        = (const int*)d_in[0];
    const int*   artists_ids    = (const int*)d_in[1];
    const int*   artists_seg    = (const int*)d_in[2];
    const int*   categories_ids = (const int*)d_in[3];
    const int*   categories_seg = (const int*)d_in[4];
    const float* user_factors   = (const float*)d_in[5];
    const float* entity_factors = (const float*)d_in[6];
    const float* relation_k     = (const float*)d_in[7];
    float* out = (float*)d_out;

    const int Ta = in_sizes[1];
    const int Tc = in_sizes[3];
    const int n_ent_elems = in_sizes[6];      // N_ENTITY * D
    const int NE = n_ent_elems / D;
    const int n4 = n_ent_elems / 4;
    const int range_sz = (NE + NPHASE - 1) / NPHASE;   // 25000 for NE=100000

    const size_t offs_bytes = (size_t)2 * (NB + 1) * sizeof(int);
    const size_t part_bytes = (size_t)2 * NPHASE * NB * sizeof(float);
    const size_t tab_bytes  = (size_t)n_ent_elems * 2;   // f16 table

    if (ws_size >= offs_bytes + part_bytes + tab_bytes) {
        int*   offs_a = (int*)d_ws;
        int*   offs_c = offs_a + (NB + 1);
        float* part   = (float*)((unsigned char*)d_ws + offs_bytes);
        uint2* efh    = (uint2*)((unsigned char*)d_ws + offs_bytes + part_bytes);

        int prep_n = n4 > Ta ? n4 : Ta;
        if (Tc > prep_n) prep_n = Tc;
        prepass<<<(prep_n + 255) / 256, 256, 0, stream>>>(
            (const float4*)entity_factors, efh, n4,
            artists_seg, Ta, offs_a,
            categories_seg, Tc, offs_c);

        // NPHASE phases x NB rows; phase = slow index
        gather_p<<<NPHASE * NB / 4, 256, 0, stream>>>(user_id,
            artists_ids, offs_a, categories_ids, offs_c,
            user_factors, (const uint4*)efh, range_sz, part);

        final_k<<<NB / 4, 256, 0, stream>>>(user_id, offs_a, offs_c,
            user_factors, relation_k, part, out);
    } else {
        aspect_fallback<<<NB / 4, 256, 0, stream>>>(user_id,
            artists_ids, artists_seg, Ta,
            categories_ids, categories_seg, Tc,
            user_factors, (const float4*)entity_factors, relation_k, out);
    }
}

// Round 8
// 77.154 us; speedup vs baseline: 2.9831x; 2.9831x over previous
//
#include <hip/hip_runtime.h>

#define NB 65536
#define D 64
#define SLOPE 0.2f

typedef _Float16 h2f __attribute__((ext_vector_type(2)));

__device__ __forceinline__ h2f as_h2(unsigned x) {
    union { unsigned u; h2f h; } v; v.u = x; return v.h;
}

struct UH { h2f h0, h1, h2, h3; };

__device__ __forceinline__ float dot8(uint4 w, const UH& u, float acc) {
#if __has_builtin(__builtin_amdgcn_fdot2)
    acc = __builtin_amdgcn_fdot2(as_h2(w.x), u.h0, acc, false);
    acc = __builtin_amdgcn_fdot2(as_h2(w.y), u.h1, acc, false);
    acc = __builtin_amdgcn_fdot2(as_h2(w.z), u.h2, acc, false);
    acc = __builtin_amdgcn_fdot2(as_h2(w.w), u.h3, acc, false);
#else
    h2f t0 = as_h2(w.x) * u.h0 + as_h2(w.y) * u.h1;
    h2f t1 = as_h2(w.z) * u.h2 + as_h2(w.w) * u.h3;
    acc += (float)t0.x + (float)t0.y + (float)t1.x + (float)t1.y;
#endif
    return acc;
}

__device__ __forceinline__ float reduce8(float v) {
#pragma unroll
    for (int off = 1; off <= 4; off <<= 1)
        v += __shfl_xor(v, off, 64);
    return v;
}
__device__ __forceinline__ float reduce64(float v) {
#pragma unroll
    for (int off = 1; off <= 32; off <<= 1)
        v += __shfl_xor(v, off, 64);
    return v;
}

__device__ __forceinline__ int lower_bound(const int* __restrict__ seg, int n, int key) {
    int lo = 0, hi = n;
    while (lo < hi) {
        int mid = (lo + hi) >> 1;
        if (seg[mid] < key) lo = mid + 1;
        else hi = mid;
    }
    return lo;
}

// merged pre-pass: fp32 -> f16 table convert (table 256B-aligned at ws+0) + offsets
__global__ __launch_bounds__(256)
void prepass(const float2* __restrict__ ef2, unsigned* __restrict__ eh, int n2,
             const int* __restrict__ a_seg, int Ta, int* __restrict__ offs_a,
             const int* __restrict__ c_seg, int Tc, int* __restrict__ offs_c)
{
    const int t = blockIdx.x * blockDim.x + threadIdx.x;
    if (t < n2) {
        float2 v = ef2[t];
        h2f h = { (_Float16)v.x, (_Float16)v.y };
        union { h2f h; unsigned u; } cv; cv.h = h;
        eh[t] = cv.u;
    }
    if (t < Ta) {
        int s = a_seg[t];
        if (t == 0) offs_a[0] = 0;
        else if (a_seg[t - 1] != s) offs_a[s] = t;
        if (t == Ta - 1) offs_a[s + 1] = Ta;
    }
    if (t < Tc) {
        int s = c_seg[t];
        if (t == 0) offs_c[0] = 0;
        else if (c_seg[t - 1] != s) offs_c[s] = t;
        if (t == Tc - 1) offs_c[s + 1] = Tc;
    }
}

// MODE: 1 = offsets + f16 table, 0 = bsearch + fp32 fallback
template<int MODE>
__global__ __launch_bounds__(256)
void aspect_kernel(const int* __restrict__ user_id,
                   const int* __restrict__ a_ids, const int* __restrict__ a_seg,
                   const int* __restrict__ offs_a, int Ta,
                   const int* __restrict__ c_ids, const int* __restrict__ c_seg,
                   const int* __restrict__ offs_c, int Tc,
                   const float* __restrict__ user_factors,
                   const float4* __restrict__ ef4,       // fp32 fallback table
                   const uint4* __restrict__ efh,        // f16 table, 8 uint4 per row (256B-aligned)
                   const float* __restrict__ relation_k,
                   float* __restrict__ out)
{
    const int wave = (blockIdx.x * blockDim.x + threadIdx.x) >> 6;
    const int lane = threadIdx.x & 63;
    const int r = lane >> 3;    // row subgroup 0..7
    const int c = lane & 7;     // dim chunk 0..7 (dims 8c..8c+7)
    const int b = wave;

    const int uid = user_id[b];
    const float4 ua = reinterpret_cast<const float4*>(user_factors)[uid * 16 + 2 * c];
    const float4 ub = reinterpret_cast<const float4*>(user_factors)[uid * 16 + 2 * c + 1];

    // ---- logits over this lane's 8 dims, reduced over the 8 c-lanes ----
    float p0 = 0.f, p1 = 0.f, p2 = 0.f;
    {
        const float uv[8] = {ua.x, ua.y, ua.z, ua.w, ub.x, ub.y, ub.z, ub.w};
#pragma unroll
        for (int j = 0; j < 8; ++j) {
            const int row = 8 * c + j;
            p0 += uv[j] * relation_k[row * 3 + 0];
            p1 += uv[j] * relation_k[row * 3 + 1];
            p2 += uv[j] * relation_k[row * 3 + 2];
        }
    }
    float l0 = reduce8(p0), l1 = reduce8(p1), l2 = reduce8(p2);
    l0 = l0 > 0.f ? l0 : SLOPE * l0;
    l1 = l1 > 0.f ? l1 : SLOPE * l1;
    l2 = l2 > 0.f ? l2 : SLOPE * l2;
    const float m  = fmaxf(l0, fmaxf(l1, l2));
    const float e0 = __expf(l0 - m);
    const float e1 = __expf(l1 - m);
    const float e2 = __expf(l2 - m);
    const float inv = 1.0f / (e0 + e1 + e2);
    const float s0 = e0 * inv, s1 = e1 * inv, s2 = e2 * inv;

    int sa, ea, sc, ec;
    if (MODE == 1) {
        sa = offs_a[b]; ea = offs_a[b + 1];
        sc = offs_c[b]; ec = offs_c[b + 1];
    } else {
        sa = lower_bound(a_seg, Ta, b); ea = lower_bound(a_seg, Ta, b + 1);
        sc = lower_bound(c_seg, Tc, b); ec = lower_bound(c_seg, Tc, b + 1);
    }

    UH uh;
    uh.h0 = h2f{ (_Float16)ua.x, (_Float16)ua.y };
    uh.h1 = h2f{ (_Float16)ua.z, (_Float16)ua.w };
    uh.h2 = h2f{ (_Float16)ub.x, (_Float16)ub.y };
    uh.h3 = h2f{ (_Float16)ub.z, (_Float16)ub.w };

    // f16 gather: 8 rows per wave-load (16 B/lane), 16 rows in flight
    auto gather_dot_f16 = [&](const int* __restrict__ ids, int s, int e) -> float {
        float acc = 0.f;
        int t = s;
        for (; t + 16 <= e; t += 16) {
            const int id0 = ids[t + r];
            const int id1 = ids[t + 8 + r];
            const uint4 w0 = efh[id0 * 8 + c];
            const uint4 w1 = efh[id1 * 8 + c];
            acc = dot8(w0, uh, acc);
            acc = dot8(w1, uh, acc);
        }
        if (t + r < e) {
            const uint4 w0 = efh[ids[t + r] * 8 + c];
            acc = dot8(w0, uh, acc);
        }
        t += 8;
        if (t < e && t + r < e) {
            const uint4 w1 = efh[ids[t + r] * 8 + c];
            acc = dot8(w1, uh, acc);
        }
        return reduce64(acc);
    };

    // fp32 fallback (R2 structure)
    auto gather_dot_f32 = [&](const int* __restrict__ ids, int s, int e) -> float {
        const int g = lane >> 4, k = lane & 15;
        const float4 u4 = reinterpret_cast<const float4*>(user_factors)[uid * 16 + k];
        float ax = 0.f, ay = 0.f, az = 0.f, aw = 0.f;
        int t = s;
        for (; t + 4 <= e; t += 4) {
            const int i0 = ids[t + g];
            const float4 v0 = ef4[i0 * 16 + k];
            ax += v0.x; ay += v0.y; az += v0.z; aw += v0.w;
        }
        if (t + g < e) {
            const int i0 = ids[t + g];
            const float4 v0 = ef4[i0 * 16 + k];
            ax += v0.x; ay += v0.y; az += v0.z; aw += v0.w;
        }
        const float part = ax * u4.x + ay * u4.y + az * u4.z + aw * u4.w;
        return reduce64(part);
    };

    float c_a, c_c;
    if (MODE == 1) {
        c_a = gather_dot_f16(a_ids, sa, ea) / (float)(ea - sa);
        c_c = gather_dot_f16(c_ids, sc, ec) / (float)(ec - sc);
    } else {
        c_a = gather_dot_f32(a_ids, sa, ea) / (float)(ea - sa);
        c_c = gather_dot_f32(c_ids, sc, ec) / (float)(ec - sc);
    }

    const float pred = (c_a * s0 + c_c * s1) / (s0 + s1);

    if (lane == 0) {
        out[b]          = pred;
        out[4 * NB + b] = c_a;
        out[5 * NB + b] = c_c;
    }
    if (lane < 3) {
        const float sv = (lane == 0) ? s0 : ((lane == 1) ? s1 : s2);
        out[NB + 3 * b + lane] = sv;
    }
}

extern "C" void kernel_launch(void* const* d_in, const int* in_sizes, int n_in,
                              void* d_out, int out_size, void* d_ws, size_t ws_size,
                              hipStream_t stream) {
    const int*   user_id        = (const int*)d_in[0];
    const int*   artists_ids    = (const int*)d_in[1];
    const int*   artists_seg    = (const int*)d_in[2];
    const int*   categories_ids = (const int*)d_in[3];
    const int*   categories_seg = (const int*)d_in[4];
    const float* user_factors   = (const float*)d_in[5];
    const float* entity_factors = (const float*)d_in[6];
    const float* relation_k     = (const float*)d_in[7];
    float* out = (float*)d_out;

    const int Ta = in_sizes[1];
    const int Tc = in_sizes[3];
    const int n_ent_elems = in_sizes[6];    // N_ENTITY * D
    const int n2 = n_ent_elems / 2;

    // layout: [f16 table (256B-aligned, rows 128B-aligned)] [offs_a] [offs_c]
    const size_t table_bytes = (size_t)n_ent_elems * 2;
    const size_t offs_bytes  = (size_t)2 * (NB + 1) * sizeof(int);
    const int blocks = NB / 4;   // one wave per row, 4 waves/block

    if (ws_size >= table_bytes + offs_bytes) {
        unsigned* efh   = (unsigned*)d_ws;
        int*      offs_a = (int*)((unsigned char*)d_ws + table_bytes);
        int*      offs_c = offs_a + (NB + 1);
        int prep_n = n2 > Ta ? n2 : Ta;
        if (Tc > prep_n) prep_n = Tc;
        prepass<<<(prep_n + 255) / 256, 256, 0, stream>>>(
            (const float2*)entity_factors, efh, n2,
            artists_seg, Ta, offs_a,
            categories_seg, Tc, offs_c);
        aspect_kernel<1><<<blocks, 256, 0, stream>>>(user_id,
            artists_ids, artists_seg, offs_a, Ta,
            categories_ids, categories_seg, offs_c, Tc,
            user_factors, (const float4*)entity_factors, (const uint4*)efh,
            relation_k, out);
    } else {
        aspect_kernel<0><<<blocks, 256, 0, stream>>>(user_id,
            artists_ids, artists_seg, nullptr, Ta,
            categories_ids, categories_seg, nullptr, Tc,
            user_factors, (const float4*)entity_factors, nullptr,
            relation_k, out);
    }
}